// Round 4
// baseline (823.937 us; speedup 1.0000x reference)
//
#include <hip/hip_runtime.h>
#include <math.h>

#define D_MODEL 2048
#define NEXP    64
#define NROWS   32768
#define SPLITS  4                   // waves per block = K-splits
#define KSPL    (D_MODEL / SPLITS)  // 512 k per wave
#define GRP     16                  // k per group: one 64B line per expert
#define BM      64                  // rows per block (= lanes per wave)

// Lane = row, acc[64] experts in VGPRs. W delivered on the VECTOR pipe with
// wave-uniform addresses (t>>6 looks divergent to LLVM -> it will NOT
// scalarize to s_load; SMEM is a dead end: OOO returns force lgkmcnt(0)
// drains, measured 10.9% VALUBusy in round 3). Vector loads return in-order
// -> fine-grained vmcnt works; explicit rotating 3-buffer prefetch, 2
// experts/chunk, covers ~180cyc L1/L2 latency. 4-way K-split per block for
// 2048 waves; deterministic LDS reduce + exact top-2 epilogue.
__global__ __launch_bounds__(256, 2) void router_kernel(
    const float* __restrict__ x,      // [NROWS, D_MODEL]
    const float* __restrict__ gw,     // [NEXP, D_MODEL]
    const float* __restrict__ bias,   // [NEXP]
    float* __restrict__ out)          // [2*NROWS weights][2*NROWS idx-as-float]
{
    __shared__ float red[SPLITS][BM][NEXP + 1];  // +1 pad: conflict-free epilogue

    const int t    = threadIdx.x;
    const int lane = t & 63;
    const int wv   = t >> 6;       // wave-uniform in reality; "divergent" to LLVM
    const int row  = blockIdx.x * BM + lane;
    const int koff = wv * KSPL;

    const float* xp  = x  + (size_t)row * D_MODEL + koff;
    const float* wp0 = gw + koff;

    float acc[NEXP];
#pragma unroll
    for (int e = 0; e < NEXP; ++e) acc[e] = 0.f;

// load 16 consecutive floats from p into flat array dst (4x b128)
#define LD16(dst, p)                                                        \
    {                                                                       \
        const float4 v0_ = ((const float4*)(p))[0];                         \
        const float4 v1_ = ((const float4*)(p))[1];                         \
        const float4 v2_ = ((const float4*)(p))[2];                         \
        const float4 v3_ = ((const float4*)(p))[3];                         \
        dst[0]  = v0_.x; dst[1]  = v0_.y; dst[2]  = v0_.z; dst[3]  = v0_.w; \
        dst[4]  = v1_.x; dst[5]  = v1_.y; dst[6]  = v1_.z; dst[7]  = v1_.w; \
        dst[8]  = v2_.x; dst[9]  = v2_.y; dst[10] = v2_.z; dst[11] = v2_.w; \
        dst[12] = v3_.x; dst[13] = v3_.y; dst[14] = v3_.z; dst[15] = v3_.w; \
    }

    float xa[GRP], xb[GRP];
    LD16(xa, xp);                    // group 0 x

    for (int g = 0; g < KSPL; g += GRP) {
        if (g + GRP < KSPL) {        // per-lane x prefetch (issued oldest)
            LD16(xb, xp + g + GRP);
        }

        // W pipeline: 32 chunks of 2 experts, rotating 3 register buffers.
        float wb[3][2 * GRP];
        LD16((wb[0] + 0),   (wp0 + 0 * D_MODEL + g));   // chunk 0: e0,e1
        LD16((wb[0] + GRP), (wp0 + 1 * D_MODEL + g));
        LD16((wb[1] + 0),   (wp0 + 2 * D_MODEL + g));   // chunk 1: e2,e3
        LD16((wb[1] + GRP), (wp0 + 3 * D_MODEL + g));

#pragma unroll
        for (int c = 0; c < NEXP / 2; ++c) {
            if (c + 2 < NEXP / 2) {  // prefetch chunk c+2 (depth 2 ~= 128cyc)
                float* wd = wb[(c + 2) % 3];
                const float* wp = wp0 + (size_t)(2 * c + 4) * D_MODEL + g;
                LD16((wd + 0),   (wp + 0));
                LD16((wd + GRP), (wp + D_MODEL));
            }
            const float* wc = wb[c % 3];
            const int e0 = 2 * c, e1 = 2 * c + 1;
#pragma unroll
            for (int j = 0; j < GRP; ++j) {
                acc[e0] = fmaf(xa[j], wc[j],       acc[e0]);
                acc[e1] = fmaf(xa[j], wc[GRP + j], acc[e1]);
            }
        }

#pragma unroll
        for (int j = 0; j < GRP; ++j) xa[j] = xb[j];
    }
#undef LD16

    // deposit this wave's K-partial: red[wv][lane][0..63]
#pragma unroll
    for (int e = 0; e < NEXP; e += 4) {
        const float4 v = make_float4(acc[e], acc[e + 1], acc[e + 2], acc[e + 3]);
        *(float4*)&red[wv][lane][e] = v;
    }
    __syncthreads();

    // epilogue: one thread per row (threads 0..63); rows stride 65 floats
    if (t < BM) {
        const int grow = blockIdx.x * BM + t;
        float m1 = -INFINITY, m2 = -INFINITY;
        int   e1 = 0, e2 = 0;
        // combine partials in fixed split order (deterministic), top-2 scan
        for (int e = 0; e < NEXP; ++e) {
            const float l = ((red[0][t][e] + red[1][t][e]) + red[2][t][e])
                            + red[3][t][e] + bias[e];
            red[0][t][e] = l;                    // stash for pass 2
            if (l > m1) { m2 = m1; e2 = e1; m1 = l; e1 = e; }
            else if (l > m2) { m2 = l; e2 = e; }
        }
        // full softmax denominator (max-subtracted), as reference
        float z = 0.f;
        for (int e = 0; e < NEXP; ++e)
            z += expf(red[0][t][e] - m1);
        const float p2    = expf(m2 - m1);
        const float denom = (1.f + p2) + 1e-8f * z;
        out[grow * 2 + 0] = 1.f / denom;
        out[grow * 2 + 1] = p2 / denom;
        float* oidx = out + 2 * NROWS;
        oidx[grow * 2 + 0] = (float)e1;
        oidx[grow * 2 + 1] = (float)e2;
    }
}

extern "C" void kernel_launch(void* const* d_in, const int* in_sizes, int n_in,
                              void* d_out, int out_size, void* d_ws, size_t ws_size,
                              hipStream_t stream) {
    const float* x    = (const float*)d_in[0];   // [32768, 2048]
    const float* gw   = (const float*)d_in[1];   // [64, 2048]
    const float* bias = (const float*)d_in[2];   // [64]
    float* out = (float*)d_out;                  // 131072 floats
    (void)in_sizes; (void)n_in; (void)out_size; (void)d_ws; (void)ws_size;

    dim3 grid(NROWS / BM);   // 512
    dim3 block(256);
    router_kernel<<<grid, block, 0, stream>>>(x, gw, bias, out);
}

// Round 5
// 724.242 us; speedup vs baseline: 1.1377x; 1.1377x over previous
//
#include <hip/hip_runtime.h>
#include <math.h>

#define D_MODEL 2048
#define NEXP    64
#define NROWS   32768
#define BROWS   128                 // rows per block
#define KSPL    512                 // k-range per wave (4-way in-block K-split)
#define BK      16                  // k per staged chunk
#define NCH     (KSPL / BK)         // 32 chunks
#define LDX     (BROWS + 4)         // 132: pad keeps 16B align, 2-way stores free
#define LDW     (NEXP + 4)          // 68

// Validated cost model (r1: predicted 164us from ds_read count, measured 167):
// CU wall = max(FMA_instrs*2/4SIMD, b128_instrs*12) -> need FMA:b128 >= 24.
// Thread tile 16 rows x 8 experts = 128 FMA : 6 b128 = 21 -> LDS floor ~61us,
// VALU floor 55us, + stage writes ~= 72us target.
// Wave = 8 row-groups x 8 expert-groups (128 rows x 64 experts); 4 waves =
// in-block K-split with PRIVATE LDS regions -> no __syncthreads in main loop.
// Grid 256 = 1 block/CU, 1 wave/SIMD; LDS latency covered by in-wave ILP
// (per-wave LDS demand is only 1/3 of its VALU time).
// Anti-spill (r4 lesson: runtime-indexed reg arrays -> scratch): launch_bounds
// (256,1) = 512-VGPR budget, constant-index arrays only, no pointer rotation.
__global__ __launch_bounds__(256, 1) void router_kernel(
    const float* __restrict__ x,      // [NROWS, D_MODEL]
    const float* __restrict__ gw,     // [NEXP, D_MODEL]
    const float* __restrict__ bias,   // [NEXP]
    float* __restrict__ out)          // [2*NROWS weights][2*NROWS idx-as-float]
{
    __shared__ alignas(16) float xs[2][4][BK][LDX];  // [dbuf][wave][k][row] 67.6KB
    __shared__ alignas(16) float ws[2][4][BK][LDW];  // [dbuf][wave][k][exp] 34.8KB
    __shared__ float red[BROWS][NEXP + 1];           // 33.3KB; total 135.7KB

    const int t    = threadIdx.x;
    const int lane = t & 63;
    const int wv   = t >> 6;        // k-split id 0..3
    const int rg   = lane >> 3;     // row group 0..7
    const int eg   = lane & 7;      // expert group 0..7
    const int R0   = blockIdx.x * BROWS;
    const int koff = wv * KSPL;

    // staging mapping: load i covers (row|exp) = 16i + (lane>>2), k-quad = lane&3
    // -> 4 consecutive lanes read one 64B line (dense 16-line coalescing)
    const int sr = lane >> 2;       // 0..15
    const int sq = lane & 3;        // 0..3
    const float* xstg = x  + (size_t)(R0 + sr) * D_MODEL + 4 * sq + koff;
    const float* wstg = gw + (size_t)sr        * D_MODEL + 4 * sq + koff;

    float acc[128];                 // [16 row-elems][8 exp-elems], const-indexed
#pragma unroll
    for (int i = 0; i < 128; ++i) acc[i] = 0.f;

    float4 xr[8], wr[4];            // global->LDS stage regs (const-indexed)

#define LOAD_REGS(KB)                                                          \
    {                                                                          \
        _Pragma("unroll")                                                      \
        for (int i = 0; i < 8; ++i)                                            \
            xr[i] = *(const float4*)(xstg + (size_t)i * 16 * D_MODEL + (KB));  \
        _Pragma("unroll")                                                      \
        for (int i = 0; i < 4; ++i)                                            \
            wr[i] = *(const float4*)(wstg + (size_t)i * 16 * D_MODEL + (KB));  \
    }

// transpose-store to [k][row]; bank = (16*(sq&1)+sr+c)%32 -> 2-way = free (m136)
#define STORE_LDS(B)                                                           \
    {                                                                          \
        _Pragma("unroll")                                                      \
        for (int i = 0; i < 8; ++i) {                                          \
            xs[B][wv][4 * sq + 0][16 * i + sr] = xr[i].x;                      \
            xs[B][wv][4 * sq + 1][16 * i + sr] = xr[i].y;                      \
            xs[B][wv][4 * sq + 2][16 * i + sr] = xr[i].z;                      \
            xs[B][wv][4 * sq + 3][16 * i + sr] = xr[i].w;                      \
        }                                                                      \
        _Pragma("unroll")                                                      \
        for (int i = 0; i < 4; ++i) {                                          \
            ws[B][wv][4 * sq + 0][16 * i + sr] = wr[i].x;                      \
            ws[B][wv][4 * sq + 1][16 * i + sr] = wr[i].y;                      \
            ws[B][wv][4 * sq + 2][16 * i + sr] = wr[i].z;                      \
            ws[B][wv][4 * sq + 3][16 * i + sr] = wr[i].w;                      \
        }                                                                      \
    }

// frag sub-blocks strided 32: 8 distinct addrs/instr start at banks
// 4*(k+rg)%32 -> all 32 banks exactly once = conflict-free; 8-lane broadcast.
#define COMPUTE(B)                                                             \
    {                                                                          \
        _Pragma("unroll")                                                      \
        for (int kk = 0; kk < BK; ++kk) {                                      \
            const float4 xf0 = *(const float4*)&xs[B][wv][kk][4 * rg + 0];     \
            const float4 xf1 = *(const float4*)&xs[B][wv][kk][4 * rg + 32];    \
            const float4 xf2 = *(const float4*)&xs[B][wv][kk][4 * rg + 64];    \
            const float4 xf3 = *(const float4*)&xs[B][wv][kk][4 * rg + 96];    \
            const float4 wf0 = *(const float4*)&ws[B][wv][kk][4 * eg + 0];     \
            const float4 wf1 = *(const float4*)&ws[B][wv][kk][4 * eg + 32];    \
            const float xv[16] = {xf0.x, xf0.y, xf0.z, xf0.w,                  \
                                  xf1.x, xf1.y, xf1.z, xf1.w,                  \
                                  xf2.x, xf2.y, xf2.z, xf2.w,                  \
                                  xf3.x, xf3.y, xf3.z, xf3.w};                 \
            const float wz[8]  = {wf0.x, wf0.y, wf0.z, wf0.w,                  \
                                  wf1.x, wf1.y, wf1.z, wf1.w};                 \
            _Pragma("unroll")                                                  \
            for (int f = 0; f < 16; ++f)                                       \
                _Pragma("unroll")                                              \
                for (int h = 0; h < 8; ++h)                                    \
                    acc[f * 8 + h] = fmaf(xv[f], wz[h], acc[f * 8 + h]);       \
        }                                                                      \
    }

    // software pipeline: globals for c+1 issue before compute(c); double-
    // buffered LDS; per-wave private regions -> no barriers needed.
    LOAD_REGS(0);
    STORE_LDS(0);
    int buf = 0;
    for (int c = 0; c < NCH; ++c) {
        if (c + 1 < NCH) LOAD_REGS((c + 1) * BK);
        COMPUTE(buf);
        if (c + 1 < NCH) STORE_LDS(buf ^ 1);
        buf ^= 1;
    }
#undef LOAD_REGS
#undef STORE_LDS
#undef COMPUTE

    // combine 4 k-partials in fixed order (w0+w1)+w2)+w3 -- bit-identical to r2
    __syncthreads();
    if (wv == 0) {
#pragma unroll
        for (int f = 0; f < 16; ++f)
#pragma unroll
            for (int h = 0; h < 8; ++h)
                red[4 * rg + 32 * (f / 4) + (f % 4)]
                   [4 * eg + 32 * (h / 4) + (h % 4)] = acc[f * 8 + h];
    }
    __syncthreads();
    if (wv == 1) {
#pragma unroll
        for (int f = 0; f < 16; ++f)
#pragma unroll
            for (int h = 0; h < 8; ++h)
                red[4 * rg + 32 * (f / 4) + (f % 4)]
                   [4 * eg + 32 * (h / 4) + (h % 4)] += acc[f * 8 + h];
    }
    __syncthreads();
    if (wv == 2) {
#pragma unroll
        for (int f = 0; f < 16; ++f)
#pragma unroll
            for (int h = 0; h < 8; ++h)
                red[4 * rg + 32 * (f / 4) + (f % 4)]
                   [4 * eg + 32 * (h / 4) + (h % 4)] += acc[f * 8 + h];
    }
    __syncthreads();
    if (wv == 3) {
#pragma unroll
        for (int f = 0; f < 16; ++f)
#pragma unroll
            for (int h = 0; h < 8; ++h)
                red[4 * rg + 32 * (f / 4) + (f % 4)]
                   [4 * eg + 32 * (h / 4) + (h % 4)] += acc[f * 8 + h];
    }
    __syncthreads();

    // epilogue: one thread per row (t<128); [65] stride -> 2-way scan reads
    if (t < BROWS) {
        const int grow = R0 + t;
        float m1 = -INFINITY, m2 = -INFINITY;
        int   e1 = 0, e2 = 0;
        for (int e = 0; e < NEXP; ++e) {
            const float l = red[t][e] + bias[e];
            if (l > m1) { m2 = m1; e2 = e1; m1 = l; e1 = e; }
            else if (l > m2) { m2 = l; e2 = e; }
        }
        float z = 0.f;
        for (int e = 0; e < NEXP; ++e)
            z += expf(red[t][e] + bias[e] - m1);
        const float p2    = expf(m2 - m1);
        const float denom = (1.f + p2) + 1e-8f * z;
        out[grow * 2 + 0] = 1.f / denom;
        out[grow * 2 + 1] = p2 / denom;
        float* oidx = out + 2 * NROWS;
        oidx[grow * 2 + 0] = (float)e1;
        oidx[grow * 2 + 1] = (float)e2;
    }
}

extern "C" void kernel_launch(void* const* d_in, const int* in_sizes, int n_in,
                              void* d_out, int out_size, void* d_ws, size_t ws_size,
                              hipStream_t stream) {
    const float* x    = (const float*)d_in[0];   // [32768, 2048]
    const float* gw   = (const float*)d_in[1];   // [64, 2048]
    const float* bias = (const float*)d_in[2];   // [64]
    float* out = (float*)d_out;                  // 131072 floats
    (void)in_sizes; (void)n_in; (void)out_size; (void)d_ws; (void)ws_size;

    dim3 grid(NROWS / BROWS);   // 256 blocks = 1 per CU
    dim3 block(256);
    router_kernel<<<grid, block, 0, stream>>>(x, gw, bias, out);
}